// Round 7
// baseline (1169.926 us; speedup 1.0000x reference)
//
#include <hip/hip_runtime.h>
#include <hip/hip_bf16.h>
#include <stdint.h>

#define N_TOK 2048
#define DM    2048
#define NEXP  64
#define TOPK  4
#define HEXP  512
#define CAPC  512
#define NSH   2
#define HSH   2048
#define RTB   8

typedef __attribute__((ext_vector_type(8))) short short8;
typedef __attribute__((ext_vector_type(4))) float f32x4;
typedef __attribute__((ext_vector_type(4))) float f4;
typedef __attribute__((ext_vector_type(4))) unsigned uint4v;

// Direct global->LDS DMA, 16B per lane. LDS dest = wave-uniform base + lane*16.
#define GLDS16(g, l) __builtin_amdgcn_global_load_lds(                     \
    (const __attribute__((address_space(1))) void*)(g),                    \
    (__attribute__((address_space(3))) void*)(l), 16, 0, 0)

// Per-wave counted VMEM wait. In-order retirement: outstanding<=N  =>
// the oldest (issued-N) loads have retired. NEVER 0 mid-loop.
#define VMWAIT(N) asm volatile("s_waitcnt vmcnt(" #N ")" ::: "memory")
#define LGKM0()   asm volatile("s_waitcnt lgkmcnt(0)" ::: "memory")

static __device__ __forceinline__ unsigned short f2bf(float f) {
  union { float f; unsigned u; } v; v.f = f;
  unsigned r = v.u + 0x7FFFu + ((v.u >> 16) & 1u);   // RNE
  return (unsigned short)(r >> 16);
}

// Bijective XCD-chunk swizzle (requires nwg % 8 == 0).
static __device__ __forceinline__ int swz_xcd(int id, int nwg) {
  return (id & 7) * (nwg >> 3) + (id >> 3);
}

// ---------------------------------------------------------------- convert x
__global__ __launch_bounds__(256) void k_convert(const float* __restrict__ x,
                                                 unsigned short* __restrict__ xb) {
  int i = (blockIdx.x * 256 + threadIdx.x) * 8;
  f4 a = *(const f4*)(x + i);
  f4 b = *(const f4*)(x + i + 4);
  short8 o;
  o[0]=f2bf(a[0]); o[1]=f2bf(a[1]); o[2]=f2bf(a[2]); o[3]=f2bf(a[3]);
  o[4]=f2bf(b[0]); o[5]=f2bf(b[1]); o[6]=f2bf(b[2]); o[7]=f2bf(b[3]);
  *(short8*)(xb + i) = o;
}

// ---------------------------------------------------------------- router
#define ARGMAX_ROUND(S,I)                                            \
  { float bv = v; int bi = lane;                                     \
    _Pragma("unroll")                                                \
    for (int o = 32; o; o >>= 1) {                                   \
      float ov = __shfl_xor(bv, o); int oi = __shfl_xor(bi, o);      \
      if (ov > bv || (ov == bv && oi < bi)) { bv = ov; bi = oi; }    \
    }                                                                \
    S = bv; I = bi; if (lane == bi) v = -1.f; }

__global__ __launch_bounds__(256) void k_router(const float* __restrict__ x,
    const float* __restrict__ Wr, const float* __restrict__ bias,
    int* __restrict__ cnt, int* __restrict__ lists, float* __restrict__ wlist) {
  __shared__ float part[4][RTB][64];
  __shared__ float logits[RTB][64];
  int t = threadIdx.x;
  int e = t & 63, sl = t >> 6;
  int tok0 = blockIdx.x * RTB;
  const float* xp = x + (size_t)tok0 * DM;
  float acc[RTB];
#pragma unroll
  for (int i = 0; i < RTB; ++i) acc[i] = 0.f;
  for (int d = sl * 512; d < sl * 512 + 512; ++d) {
    float w = Wr[(size_t)d * NEXP + e];
#pragma unroll
    for (int i = 0; i < RTB; ++i) acc[i] += xp[(size_t)i * DM + d] * w;
  }
#pragma unroll
  for (int i = 0; i < RTB; ++i) part[sl][i][e] = acc[i];
  __syncthreads();
  for (int i = sl; i < RTB; i += 4)
    logits[i][e] = part[0][i][e] + part[1][i][e] + part[2][i][e] + part[3][i][e] + bias[e];
  __syncthreads();
  int lane = t & 63, wv = t >> 6;
  for (int i = wv * 2; i < wv * 2 + 2; ++i) {
    float lg = logits[i][lane];
    float m = lg;
#pragma unroll
    for (int o = 32; o; o >>= 1) m = fmaxf(m, __shfl_xor(m, o));
    float p = expf(lg - m);
    float sm = p;
#pragma unroll
    for (int o = 32; o; o >>= 1) sm += __shfl_xor(sm, o);
    float v = p / sm;
    float s0, s1, s2, s3; int i0, i1, i2, i3;
    ARGMAX_ROUND(s0, i0)
    ARGMAX_ROUND(s1, i1)
    ARGMAX_ROUND(s2, i2)
    ARGMAX_ROUND(s3, i3)
    float tot = s0 + s1 + s2 + s3;
    if (lane < TOPK) {
      float myw = (lane == 0 ? s0 : lane == 1 ? s1 : lane == 2 ? s2 : s3) / tot;
      int   mye = (lane == 0 ? i0 : lane == 1 ? i1 : lane == 2 ? i2 : i3);
      int pos = atomicAdd(&cnt[mye], 1);
      if (pos < CAPC) {
        lists[mye * CAPC + pos] = tok0 + i;
        wlist[mye * CAPC + pos] = myw;
      }
    }
  }
}

// ---------------------------------------------------------------- offsets
__global__ void k_offs(const int* __restrict__ cnt, int* __restrict__ offs) {
  int l = threadIdx.x;            // 64 threads
  int c = min(cnt[l], CAPC);
  int sum = c;
#pragma unroll
  for (int o = 1; o < 64; o <<= 1) {
    int ov = __shfl_up(sum, o);
    if (l >= o) sum += ov;
  }
  offs[l + 1] = sum;
  if (l == 0) offs[0] = 0;
}

// ---------------------------------------------------------------- wave-GEMM pieces
// Wave-independent: NO barriers. Each wave owns rows [wm, wm+64) and the
// block's 16 output cols. A: wave-private LDS [2][64 r][32 k] bf16 (64B rows,
// GLDS-linear dest, source chunk pre-permuted c^=(row>>1)&3, read XOR
// byte^=((row>>1)&3)<<4 — measured 0-conflict pattern). B: global->VGPR,
// 8 fp32 dwords per matrix per tile + v_cvt_pk_bf16_f32.

static __device__ __forceinline__ short8 frag_ldA(const unsigned short* lds, int row, int kElem) {
  int byte = row * 64 + kElem * 2;
  byte ^= ((row >> 1) & 3) << 4;
  return *(const short8*)((const char*)lds + byte);
}

static __device__ __forceinline__ short8 bfrag(const float (&b)[8]) {
  unsigned u0, u1, u2, u3;
  asm("v_cvt_pk_bf16_f32 %0, %1, %2" : "=v"(u0) : "v"(b[0]), "v"(b[1]));
  asm("v_cvt_pk_bf16_f32 %0, %1, %2" : "=v"(u1) : "v"(b[2]), "v"(b[3]));
  asm("v_cvt_pk_bf16_f32 %0, %1, %2" : "=v"(u2) : "v"(b[4]), "v"(b[5]));
  asm("v_cvt_pk_bf16_f32 %0, %1, %2" : "=v"(u3) : "v"(b[6]), "v"(b[7]));
  uint4v uv = {u0, u1, u2, u3};
  return __builtin_bit_cast(short8, uv);
}

static __device__ __forceinline__ float silu_mul(float g, float u) {
  return g / (1.f + expf(-g)) * u;
}

// A source pointers (4 GLDS rounds/tile). Round p: local row = p*16+(lane>>2),
// 16B chunk = lane&3, pre-swizzled.
#define A_SETUP(asrc, SROW_EXPR)                                            \
  const unsigned short* asrc[4];                                            \
  { _Pragma("unroll") for (int p = 0; p < 4; ++p) {                         \
      int row = p * 16 + (lane >> 2);                                       \
      int srow = (SROW_EXPR);                                               \
      asrc[p] = Abase + (size_t)srow * lda                                  \
              + (((lane & 3) ^ ((row >> 1) & 3)) << 3); } }

#define A_ISSUE(P, k0)                                                      \
  { _Pragma("unroll") for (int p = 0; p < 4; ++p)                           \
      GLDS16(asrc[p] + (k0), &lA[wv][P][0] + p * 512); }

// B loads: Bl pre-offset by kbm*ldb + (n0 + r16). 8 dwords, stride ldb.
#define B_LOAD(dst, Bl, kt, ldb)                                            \
  { _Pragma("unroll") for (int j = 0; j < 8; ++j)                           \
      dst[j] = (Bl)[((size_t)(kt) * 32 + j) * (size_t)(ldb)]; }

// ---------------------------------------------------------------- expert gate+up
// grid 2048 = 64 e x 32 nb (BN=16). waves stack M (4x64=256 >= typical ne).
__global__ __launch_bounds__(256, 4) void k_expert_gateup(const unsigned short* __restrict__ xbf,
    const float* __restrict__ Wg, const float* __restrict__ Wu,
    const int* __restrict__ cnt, const int* __restrict__ offs,
    const int* __restrict__ lists, unsigned short* __restrict__ hws) {
  int bid = swz_xcd(blockIdx.x, NEXP * (HEXP / 16));
  int e  = bid >> 5;
  int n0 = (bid & 31) * 16;
  int ne = min(cnt[e], CAPC);
  if (ne == 0) return;
  const int* lst = lists + e * CAPC;
  int base = offs[e];
  __shared__ unsigned short lA[4][2][2048];
  int lane = threadIdx.x & 63, wv = threadIdx.x >> 6;
  int wm = wv * 64;
  int r16 = lane & 15;
  int kbm = (lane >> 4) * 8;
  const unsigned short* Abase = xbf; const int lda = DM;
  const float* Bgl = Wg + (size_t)e * DM * HEXP + (size_t)kbm * HEXP + n0 + r16;
  const float* Bul = Wu + (size_t)e * DM * HEXP + (size_t)kbm * HEXP + n0 + r16;
  const int NT = DM / 32;           // 64
  for (int m0 = 0; m0 < ne; m0 += 256) {
    if (m0 + wm >= ne) continue;    // idle wave: no barriers, just skip
    A_SETUP(asrc, lst[min(m0 + wm + row, ne - 1)])
    f32x4 accg[4] = {}; f32x4 accu[4] = {};
    float bg0[8], bu0[8], bg1[8], bu1[8];
    A_ISSUE(0, 0)  B_LOAD(bg0, Bgl, 0, HEXP) B_LOAD(bu0, Bul, 0, HEXP)
    A_ISSUE(1, 32) B_LOAD(bg1, Bgl, 1, HEXP) B_LOAD(bu1, Bul, 1, HEXP)
#pragma unroll 1
    for (int t = 0; t < NT; t += 2) {
      VMWAIT(20);                            // drain tile t (oldest 20)
      {
        short8 fg = bfrag(bg0), fu = bfrag(bu0);
#pragma unroll
        for (int mf = 0; mf < 4; ++mf) {
          short8 av = frag_ldA(&lA[wv][0][0], mf * 16 + r16, kbm);
          accg[mf] = __builtin_amdgcn_mfma_f32_16x16x32_bf16(av, fg, accg[mf], 0, 0, 0);
          accu[mf] = __builtin_amdgcn_mfma_f32_16x16x32_bf16(av, fu, accu[mf], 0, 0, 0);
        }
      }
      LGKM0();                               // frag reads done before buf reuse
      if (t + 2 < NT) {
        A_ISSUE(0, (t + 2) * 32) B_LOAD(bg0, Bgl, t + 2, HEXP) B_LOAD(bu0, Bul, t + 2, HEXP)
        VMWAIT(20);                          // drain tile t+1
      } else { VMWAIT(0); }
      {
        short8 fg = bfrag(bg1), fu = bfrag(bu1);
#pragma unroll
        for (int mf = 0; mf < 4; ++mf) {
          short8 av = frag_ldA(&lA[wv][1][0], mf * 16 + r16, kbm);
          accg[mf] = __builtin_amdgcn_mfma_f32_16x16x32_bf16(av, fg, accg[mf], 0, 0, 0);
          accu[mf] = __builtin_amdgcn_mfma_f32_16x16x32_bf16(av, fu, accu[mf], 0, 0, 0);
        }
      }
      LGKM0();
      if (t + 3 < NT) {
        A_ISSUE(1, (t + 3) * 32) B_LOAD(bg1, Bgl, t + 3, HEXP) B_LOAD(bu1, Bul, t + 3, HEXP)
      }
    }
#pragma unroll
    for (int mf = 0; mf < 4; ++mf)
#pragma unroll
      for (int r = 0; r < 4; ++r) {
        int rl = m0 + wm + mf * 16 + (lane >> 4) * 4 + r;
        if (rl < ne) {
          float h = silu_mul(accg[mf][r], accu[mf][r]);
          hws[(size_t)(base + rl) * HEXP + n0 + r16] = f2bf(h);
        }
      }
  }
}

// ---------------------------------------------------------------- shared gate+up
// grid 2048 = 2 s x 8 mb x 128 nb
__global__ __launch_bounds__(256, 4) void k_shared_gateup(const unsigned short* __restrict__ xbf,
    const float* __restrict__ Sg, const float* __restrict__ Su,
    unsigned short* __restrict__ hs) {
  int bid = swz_xcd(blockIdx.x, NSH * (N_TOK / 256) * (HSH / 16));
  int nb = bid & 127, mb = (bid >> 7) & 7, s = bid >> 10;
  int n0 = nb * 16, m0 = mb * 256;
  __shared__ unsigned short lA[4][2][2048];
  int lane = threadIdx.x & 63, wv = threadIdx.x >> 6;
  int wm = wv * 64;
  int r16 = lane & 15;
  int kbm = (lane >> 4) * 8;
  const unsigned short* Abase = xbf; const int lda = DM;
  const float* Bgl = Sg + (size_t)s * DM * HSH + (size_t)kbm * HSH + n0 + r16;
  const float* Bul = Su + (size_t)s * DM * HSH + (size_t)kbm * HSH + n0 + r16;
  const int NT = DM / 32;           // 64
  A_SETUP(asrc, m0 + wm + row)
  f32x4 accg[4] = {}; f32x4 accu[4] = {};
  float bg0[8], bu0[8], bg1[8], bu1[8];
  A_ISSUE(0, 0)  B_LOAD(bg0, Bgl, 0, HSH) B_LOAD(bu0, Bul, 0, HSH)
  A_ISSUE(1, 32) B_LOAD(bg1, Bgl, 1, HSH) B_LOAD(bu1, Bul, 1, HSH)
#pragma unroll 1
  for (int t = 0; t < NT; t += 2) {
    VMWAIT(20);
    {
      short8 fg = bfrag(bg0), fu = bfrag(bu0);
#pragma unroll
      for (int mf = 0; mf < 4; ++mf) {
        short8 av = frag_ldA(&lA[wv][0][0], mf * 16 + r16, kbm);
        accg[mf] = __builtin_amdgcn_mfma_f32_16x16x32_bf16(av, fg, accg[mf], 0, 0, 0);
        accu[mf] = __builtin_amdgcn_mfma_f32_16x16x32_bf16(av, fu, accu[mf], 0, 0, 0);
      }
    }
    LGKM0();
    if (t + 2 < NT) {
      A_ISSUE(0, (t + 2) * 32) B_LOAD(bg0, Bgl, t + 2, HSH) B_LOAD(bu0, Bul, t + 2, HSH)
      VMWAIT(20);
    } else { VMWAIT(0); }
    {
      short8 fg = bfrag(bg1), fu = bfrag(bu1);
#pragma unroll
      for (int mf = 0; mf < 4; ++mf) {
        short8 av = frag_ldA(&lA[wv][1][0], mf * 16 + r16, kbm);
        accg[mf] = __builtin_amdgcn_mfma_f32_16x16x32_bf16(av, fg, accg[mf], 0, 0, 0);
        accu[mf] = __builtin_amdgcn_mfma_f32_16x16x32_bf16(av, fu, accu[mf], 0, 0, 0);
      }
    }
    LGKM0();
    if (t + 3 < NT) {
      A_ISSUE(1, (t + 3) * 32) B_LOAD(bg1, Bgl, t + 3, HSH) B_LOAD(bu1, Bul, t + 3, HSH)
    }
  }
#pragma unroll
  for (int mf = 0; mf < 4; ++mf)
#pragma unroll
    for (int r = 0; r < 4; ++r) {
      int row = m0 + wm + mf * 16 + (lane >> 4) * 4 + r;
      float h = silu_mul(accg[mf][r], accu[mf][r]);
      hs[(size_t)row * (NSH * HSH) + s * HSH + n0 + r16] = f2bf(h);
    }
}

// ---------------------------------------------------------------- shared down
// grid 1024 = 8 mb x 128 nb
__global__ __launch_bounds__(256, 4) void k_shared_down(const unsigned short* __restrict__ hs,
    const float* __restrict__ Sd, float* __restrict__ out) {
  int bid = swz_xcd(blockIdx.x, (N_TOK / 256) * (DM / 16));
  int nb = bid & 127, mb = bid >> 7;
  int n0 = nb * 16, m0 = mb * 256;
  __shared__ unsigned short lA[4][2][2048];
  int lane = threadIdx.x & 63, wv = threadIdx.x >> 6;
  int wm = wv * 64;
  int r16 = lane & 15;
  int kbm = (lane >> 4) * 8;
  const unsigned short* Abase = hs; const int lda = NSH * HSH;
  const float* Bl = Sd + (size_t)kbm * DM + n0 + r16;
  const int NT = (NSH * HSH) / 32;  // 128
  A_SETUP(asrc, m0 + wm + row)
  f32x4 acc[4] = {};
  float b0[8], b1[8];
  A_ISSUE(0, 0)  B_LOAD(b0, Bl, 0, DM)
  A_ISSUE(1, 32) B_LOAD(b1, Bl, 1, DM)
#pragma unroll 1
  for (int t = 0; t < NT; t += 2) {
    VMWAIT(12);
    {
      short8 fb = bfrag(b0);
#pragma unroll
      for (int mf = 0; mf < 4; ++mf) {
        short8 av = frag_ldA(&lA[wv][0][0], mf * 16 + r16, kbm);
        acc[mf] = __builtin_amdgcn_mfma_f32_16x16x32_bf16(av, fb, acc[mf], 0, 0, 0);
      }
    }
    LGKM0();
    if (t + 2 < NT) {
      A_ISSUE(0, (t + 2) * 32) B_LOAD(b0, Bl, t + 2, DM)
      VMWAIT(12);
    } else { VMWAIT(0); }
    {
      short8 fb = bfrag(b1);
#pragma unroll
      for (int mf = 0; mf < 4; ++mf) {
        short8 av = frag_ldA(&lA[wv][1][0], mf * 16 + r16, kbm);
        acc[mf] = __builtin_amdgcn_mfma_f32_16x16x32_bf16(av, fb, acc[mf], 0, 0, 0);
      }
    }
    LGKM0();
    if (t + 3 < NT) {
      A_ISSUE(1, (t + 3) * 32) B_LOAD(b1, Bl, t + 3, DM)
    }
  }
#pragma unroll
  for (int mf = 0; mf < 4; ++mf)
#pragma unroll
    for (int r = 0; r < 4; ++r) {
      int row = m0 + wm + mf * 16 + (lane >> 4) * 4 + r;
      out[(size_t)row * DM + n0 + r16] = acc[mf][r];
    }
}

// ---------------------------------------------------------------- expert down
// grid 8192 = 64 e x 128 nb
__global__ __launch_bounds__(256, 4) void k_expert_down(const unsigned short* __restrict__ hws,
    const float* __restrict__ Wd, const int* __restrict__ cnt, const int* __restrict__ offs,
    const int* __restrict__ lists, const float* __restrict__ wlist,
    float* __restrict__ out) {
  int bid = swz_xcd(blockIdx.x, NEXP * (DM / 16));
  int e  = bid >> 7;
  int n0 = (bid & 127) * 16;
  int ne = min(cnt[e], CAPC);
  if (ne == 0) return;
  __shared__ unsigned short lA[4][2][2048];
  int lane = threadIdx.x & 63, wv = threadIdx.x >> 6;
  int wm = wv * 64;
  int r16 = lane & 15;
  int kbm = (lane >> 4) * 8;
  const unsigned short* Abase = hws + (size_t)offs[e] * HEXP; const int lda = HEXP;
  const float* Bl = Wd + (size_t)e * HEXP * DM + (size_t)kbm * DM + n0 + r16;
  const int NT = HEXP / 32;         // 16
  for (int m0 = 0; m0 < ne; m0 += 256) {
    if (m0 + wm >= ne) continue;
    A_SETUP(asrc, min(m0 + wm + row, ne - 1))
    f32x4 acc[4] = {};
    float b0[8], b1[8];
    A_ISSUE(0, 0)  B_LOAD(b0, Bl, 0, DM)
    A_ISSUE(1, 32) B_LOAD(b1, Bl, 1, DM)
#pragma unroll 1
    for (int t = 0; t < NT; t += 2) {
      VMWAIT(12);
      {
        short8 fb = bfrag(b0);
#pragma unroll
        for (int mf = 0; mf < 4; ++mf) {
          short8 av = frag_ldA(&lA[wv][0][0], mf * 16 + r16, kbm);
          acc[mf] = __builtin_amdgcn_mfma_f32_16x16x32_bf16(av, fb, acc[mf], 0, 0, 0);
        }
      }
      LGKM0();
      if (t + 2 < NT) {
        A_ISSUE(0, (t + 2) * 32) B_LOAD(b0, Bl, t + 2, DM)
        VMWAIT(12);
      } else { VMWAIT(0); }
      {
        short8 fb = bfrag(b1);
#pragma unroll
        for (int mf = 0; mf < 4; ++mf) {
          short8 av = frag_ldA(&lA[wv][1][0], mf * 16 + r16, kbm);
          acc[mf] = __builtin_amdgcn_mfma_f32_16x16x32_bf16(av, fb, acc[mf], 0, 0, 0);
        }
      }
      LGKM0();
      if (t + 3 < NT) {
        A_ISSUE(1, (t + 3) * 32) B_LOAD(b1, Bl, t + 3, DM)
      }
    }
#pragma unroll
    for (int mf = 0; mf < 4; ++mf)
#pragma unroll
      for (int r = 0; r < 4; ++r) {
        int rl = m0 + wm + mf * 16 + (lane >> 4) * 4 + r;
        if (rl < ne) {
          int tok  = lists[e * CAPC + rl];
          float w  = wlist[e * CAPC + rl];
          atomicAdd(out + (size_t)tok * DM + n0 + r16, acc[mf][r] * w);
        }
      }
  }
}

// ---------------------------------------------------------------- launch
extern "C" void kernel_launch(void* const* d_in, const int* in_sizes, int n_in,
                              void* d_out, int out_size, void* d_ws, size_t ws_size,
                              hipStream_t stream) {
  const float* x    = (const float*)d_in[0];
  const float* Wr   = (const float*)d_in[1];
  const float* bias = (const float*)d_in[2];
  const float* Wg   = (const float*)d_in[3];
  const float* Wu   = (const float*)d_in[4];
  const float* Wd   = (const float*)d_in[5];
  const float* Sg   = (const float*)d_in[6];
  const float* Su   = (const float*)d_in[7];
  const float* Sd   = (const float*)d_in[8];
  float* out = (float*)d_out;
  char* ws = (char*)d_ws;

  const size_t off_cnt   = 0;
  const size_t off_offs  = 256;
  const size_t off_lists = 1024;
  const size_t off_wlist = off_lists + (size_t)NEXP * CAPC * 4;
  const size_t off_xbf   = off_wlist + (size_t)NEXP * CAPC * 4;
  const size_t off_hs    = off_xbf + (size_t)N_TOK * DM * 2;
  const size_t off_h     = off_hs + (size_t)N_TOK * NSH * HSH * 2;
  const size_t req       = off_h + (size_t)N_TOK * TOPK * HEXP * 2;
  if (ws_size < req) return;   // loud failure, no corruption

  int* cnt            = (int*)(ws + off_cnt);
  int* offs           = (int*)(ws + off_offs);
  int* lists          = (int*)(ws + off_lists);
  float* wlist        = (float*)(ws + off_wlist);
  unsigned short* xbf = (unsigned short*)(ws + off_xbf);
  unsigned short* hs  = (unsigned short*)(ws + off_hs);
  unsigned short* hws = (unsigned short*)(ws + off_h);

  hipMemsetAsync(cnt, 0, NEXP * sizeof(int), stream);
  k_convert<<<(N_TOK * DM) / (256 * 8), 256, 0, stream>>>(x, xbf);
  k_router<<<N_TOK / RTB, 256, 0, stream>>>(x, Wr, bias, cnt, lists, wlist);
  k_offs<<<1, 64, 0, stream>>>(cnt, offs);
  k_expert_gateup<<<NEXP * (HEXP / 16), 256, 0, stream>>>(xbf, Wg, Wu, cnt, offs, lists, hws);
  k_shared_gateup<<<NSH * (N_TOK / 256) * (HSH / 16), 256, 0, stream>>>(xbf, Sg, Su, hs);
  k_shared_down<<<(N_TOK / 256) * (DM / 16), 256, 0, stream>>>(hs, Sd, out);
  k_expert_down<<<NEXP * (DM / 16), 256, 0, stream>>>(hws, Wd, cnt, offs, lists, wlist, out);
}

// Round 9
// 727.606 us; speedup vs baseline: 1.6079x; 1.6079x over previous
//
#include <hip/hip_runtime.h>
#include <hip/hip_bf16.h>
#include <stdint.h>

#define N_TOK 2048
#define DM    2048
#define NEXP  64
#define TOPK  4
#define HEXP  512
#define CAPC  512
#define NSH   2
#define HSH   2048
#define RTB   8

typedef __attribute__((ext_vector_type(8))) short short8;
typedef __attribute__((ext_vector_type(4))) float f32x4;
typedef __attribute__((ext_vector_type(4))) float f4;
typedef __attribute__((ext_vector_type(4))) unsigned uint4v;

#define GLDS16(g, l) __builtin_amdgcn_global_load_lds(                     \
    (const __attribute__((address_space(1))) void*)(g),                    \
    (__attribute__((address_space(3))) void*)(l), 16, 0, 0)

#define VMWAIT(N) asm volatile("s_waitcnt vmcnt(" #N ")" ::: "memory")
#define LGKM0()   asm volatile("s_waitcnt lgkmcnt(0)" ::: "memory")
#define BARX() do { asm volatile("" ::: "memory");                          \
                    __builtin_amdgcn_s_barrier();                           \
                    asm volatile("" ::: "memory"); } while (0)
#define MEMCLOB() asm volatile("" ::: "memory")

static __device__ __forceinline__ unsigned short f2bf(float f) {
  union { float f; unsigned u; } v; v.f = f;
  unsigned r = v.u + 0x7FFFu + ((v.u >> 16) & 1u);   // RNE
  return (unsigned short)(r >> 16);
}

// ---------------------------------------------------------------- convert x
__global__ __launch_bounds__(256) void k_convert(const float* __restrict__ x,
                                                 unsigned short* __restrict__ xb) {
  int i = (blockIdx.x * 256 + threadIdx.x) * 8;
  f4 a = *(const f4*)(x + i);
  f4 b = *(const f4*)(x + i + 4);
  short8 o;
  o[0]=f2bf(a[0]); o[1]=f2bf(a[1]); o[2]=f2bf(a[2]); o[3]=f2bf(a[3]);
  o[4]=f2bf(b[0]); o[5]=f2bf(b[1]); o[6]=f2bf(b[2]); o[7]=f2bf(b[3]);
  *(short8*)(xb + i) = o;
}

// ---------------------------------------------------------------- router
#define ARGMAX_ROUND(S,I)                                            \
  { float bv = v; int bi = lane;                                     \
    _Pragma("unroll")                                                \
    for (int o = 32; o; o >>= 1) {                                   \
      float ov = __shfl_xor(bv, o); int oi = __shfl_xor(bi, o);      \
      if (ov > bv || (ov == bv && oi < bi)) { bv = ov; bi = oi; }    \
    }                                                                \
    S = bv; I = bi; if (lane == bi) v = -1.f; }

__global__ __launch_bounds__(256) void k_router(const float* __restrict__ x,
    const float* __restrict__ Wr, const float* __restrict__ bias,
    int* __restrict__ cnt, int* __restrict__ lists, float* __restrict__ wlist) {
  __shared__ float part[4][RTB][64];
  __shared__ float logits[RTB][64];
  int t = threadIdx.x;
  int e = t & 63, sl = t >> 6;
  int tok0 = blockIdx.x * RTB;
  const float* xp = x + (size_t)tok0 * DM;
  float acc[RTB];
#pragma unroll
  for (int i = 0; i < RTB; ++i) acc[i] = 0.f;
  for (int d = sl * 512; d < sl * 512 + 512; ++d) {
    float w = Wr[(size_t)d * NEXP + e];
#pragma unroll
    for (int i = 0; i < RTB; ++i) acc[i] += xp[(size_t)i * DM + d] * w;
  }
#pragma unroll
  for (int i = 0; i < RTB; ++i) part[sl][i][e] = acc[i];
  __syncthreads();
  for (int i = sl; i < RTB; i += 4)
    logits[i][e] = part[0][i][e] + part[1][i][e] + part[2][i][e] + part[3][i][e] + bias[e];
  __syncthreads();
  int lane = t & 63, wv = t >> 6;
  for (int i = wv * 2; i < wv * 2 + 2; ++i) {
    float lg = logits[i][lane];
    float m = lg;
#pragma unroll
    for (int o = 32; o; o >>= 1) m = fmaxf(m, __shfl_xor(m, o));
    float p = expf(lg - m);
    float sm = p;
#pragma unroll
    for (int o = 32; o; o >>= 1) sm += __shfl_xor(sm, o);
    float v = p / sm;
    float s0, s1, s2, s3; int i0, i1, i2, i3;
    ARGMAX_ROUND(s0, i0)
    ARGMAX_ROUND(s1, i1)
    ARGMAX_ROUND(s2, i2)
    ARGMAX_ROUND(s3, i3)
    float tot = s0 + s1 + s2 + s3;
    if (lane < TOPK) {
      float myw = (lane == 0 ? s0 : lane == 1 ? s1 : lane == 2 ? s2 : s3) / tot;
      int   mye = (lane == 0 ? i0 : lane == 1 ? i1 : lane == 2 ? i2 : i3);
      int pos = atomicAdd(&cnt[mye], 1);
      if (pos < CAPC) {
        lists[mye * CAPC + pos] = tok0 + i;
        wlist[mye * CAPC + pos] = myw;
      }
    }
  }
}

// ---------------------------------------------------------------- offsets
__global__ void k_offs(const int* __restrict__ cnt, int* __restrict__ offs) {
  int l = threadIdx.x;
  int c = min(cnt[l], CAPC);
  int sum = c;
#pragma unroll
  for (int o = 1; o < 64; o <<= 1) {
    int ov = __shfl_up(sum, o);
    if (l >= o) sum += ov;
  }
  offs[l + 1] = sum;
  if (l == 0) offs[0] = 0;
}

// ---------------------------------------------------------------- shared helpers (R4-proven)
static __device__ __forceinline__ short8 frag_ldA(const unsigned short* lds, int row, int kElem) {
  int byte = row * 64 + kElem * 2;
  byte ^= ((row >> 1) & 3) << 4;
  return *(const short8*)((const char*)lds + byte);
}

static __device__ __forceinline__ short8 bfragB(const float* lB, int nl, int kb) {
  const float* p = lB + kb * 64 + (nl ^ (((kb >> 3) & 1) << 4));
  float f0 = p[0],   f1 = p[64],  f2 = p[128], f3 = p[192];
  float f4_ = p[256], f5 = p[320], f6 = p[384], f7 = p[448];
  unsigned u0, u1, u2, u3;
  asm("v_cvt_pk_bf16_f32 %0, %1, %2" : "=v"(u0) : "v"(f0),  "v"(f1));
  asm("v_cvt_pk_bf16_f32 %0, %1, %2" : "=v"(u1) : "v"(f2),  "v"(f3));
  asm("v_cvt_pk_bf16_f32 %0, %1, %2" : "=v"(u2) : "v"(f4_), "v"(f5));
  asm("v_cvt_pk_bf16_f32 %0, %1, %2" : "=v"(u3) : "v"(f6),  "v"(f7));
  uint4v uv = {u0, u1, u2, u3};
  return __builtin_bit_cast(short8, uv);
}

static __device__ __forceinline__ void mma1f(const unsigned short* lA, const float* lB,
    f32x4 (&acc)[4][2], int wm, int wn, int lane) {
  int r16 = lane & 15;
  int kb  = (lane >> 4) * 8;
  short8 a[4], b[2];
#pragma unroll
  for (int mf = 0; mf < 4; ++mf) a[mf] = frag_ldA(lA, wm + mf * 16 + r16, kb);
#pragma unroll
  for (int nf = 0; nf < 2; ++nf) b[nf] = bfragB(lB, wn + nf * 16 + r16, kb);
#pragma unroll
  for (int mf = 0; mf < 4; ++mf)
#pragma unroll
    for (int nf = 0; nf < 2; ++nf)
      acc[mf][nf] = __builtin_amdgcn_mfma_f32_16x16x32_bf16(a[mf], b[nf], acc[mf][nf], 0, 0, 0);
}

static __device__ __forceinline__ void mma2f(const unsigned short* lA,
    const float* lBg, const float* lBu,
    f32x4 (&accg)[4][2], f32x4 (&accu)[4][2], int wm, int wn, int lane) {
  int r16 = lane & 15;
  int kb  = (lane >> 4) * 8;
  short8 a[4], bg[2], bu[2];
#pragma unroll
  for (int mf = 0; mf < 4; ++mf) a[mf] = frag_ldA(lA, wm + mf * 16 + r16, kb);
#pragma unroll
  for (int nf = 0; nf < 2; ++nf) {
    bg[nf] = bfragB(lBg, wn + nf * 16 + r16, kb);
    bu[nf] = bfragB(lBu, wn + nf * 16 + r16, kb);
  }
#pragma unroll
  for (int mf = 0; mf < 4; ++mf)
#pragma unroll
    for (int nf = 0; nf < 2; ++nf) {
      accg[mf][nf] = __builtin_amdgcn_mfma_f32_16x16x32_bf16(a[mf], bg[nf], accg[mf][nf], 0, 0, 0);
      accu[mf][nf] = __builtin_amdgcn_mfma_f32_16x16x32_bf16(a[mf], bu[nf], accu[mf][nf], 0, 0, 0);
    }
}

static __device__ __forceinline__ float silu_mul(float g, float u) {
  return g / (1.f + expf(-g)) * u;
}

#define A_SETUP(asrc, SROW_EXPR)                                            \
  const unsigned short* asrc[2];                                            \
  {                                                                         \
    _Pragma("unroll")                                                       \
    for (int p = 0; p < 2; ++p) {                                           \
      int row = p * 64 + wv * 16 + (lane >> 2);                             \
      int srow = (SROW_EXPR);                                               \
      asrc[p] = Abase + (size_t)srow * lda                                  \
              + (((lane & 3) ^ ((row >> 1) & 3)) << 3);                     \
    }                                                                       \
  }
#define A_STAGE(asrc, lAbuf, k0)                                            \
  { _Pragma("unroll")                                                       \
    for (int p = 0; p < 2; ++p)                                             \
      GLDS16(asrc[p] + (k0), (lAbuf) + p * 2048 + wv * 512); }

#define B_SETUP(bsrc, Bbase, ldb)                                           \
  const float* bsrc[2];                                                     \
  {                                                                         \
    _Pragma("unroll")                                                       \
    for (int p = 0; p < 2; ++p) {                                           \
      int k = p * 16 + wv * 4 + (lane >> 4);                                \
      int c = (lane & 15) ^ (((k >> 3) & 1) << 2);                          \
      bsrc[p] = (Bbase) + (size_t)k * (ldb) + n0 + c * 4;                   \
    }                                                                       \
  }
#define B_STAGE(bsrc, lBbuf, k0, ldb)                                       \
  { _Pragma("unroll")                                                       \
    for (int p = 0; p < 2; ++p)                                             \
      GLDS16(bsrc[p] + (size_t)(k0) * (ldb), (lBbuf) + p * 1024 + wv * 256); }

// ================================================================ expert gate+up, streaming split-K
// grid 1024: bid -> r=bid&7, ns=(bid>>3)&1, q=bid>>4; pair=q*8+r; e=pair>>3,
// mat=(pair>>2)&1, ks=pair&3. Block (512 thr, 8 waves) computes the partial
// C[e-tokens 0..127][256 n-half] over k-slice [ks*512, ks*512+512) for ONE
// matrix (g or u), streaming the weight region CONTIGUOUSLY (1KB row-halves
// via dwordx4), and atomicAdds fp32 partials into accg/accu.
__global__ __launch_bounds__(512, 2) void k_expert_gu_mm(const unsigned short* __restrict__ xbf,
    const float* __restrict__ Wg, const float* __restrict__ Wu,
    const int* __restrict__ cnt, const int* __restrict__ offs,
    const int* __restrict__ lists, float* __restrict__ accg, float* __restrict__ accu) {
  int bid = blockIdx.x;
  int r8 = bid & 7, ns = (bid >> 3) & 1, q = bid >> 4;
  int pair = q * 8 + r8;
  int e = pair >> 3, mat = (pair >> 2) & 1, ks = pair & 3;
  int ne = min(cnt[e], CAPC);
  if (ne == 0) return;
  const int* lst = lists + e * CAPC;
  int base = offs[e];
  const float* W = (mat ? Wu : Wg) + (size_t)e * DM * HEXP;
  float* accb = mat ? accu : accg;
  int kr = ks * 512;          // k-slice base
  int nr = ns * 256;          // n-half base

  __shared__ unsigned short lA[2][128 * 32];   // bf16 [128][32], 64B rows, swizzled
  __shared__ unsigned short lB[2][32 * 256];   // bf16 [32][256], chunk-swizzled

  int tid = threadIdx.x;
  int lane = tid & 63, wv = tid >> 6;          // 8 waves
  int wm = (wv >> 2) * 64, wn = (wv & 3) * 64; // wave tile [64 m][64 n]
  int r16 = lane & 15;
  int kb  = (lane >> 4) * 8;

  // B staging geometry: thread covers row kB = tid>>4, 16 floats at (tid&15)*16.
  int kB = tid >> 4;
  int nB = (tid & 15) * 16;
  int swzB = (kB & 7) ^ ((kB >> 3) << 1);
  const float* Wrow = W + (size_t)(kr + kB) * HEXP + nr + nB;  // + t*32*HEXP per step
  int wb_off  = kB * 512 + ((((nB >> 3) ^ swzB) & 31) << 4);
  int wb_off2 = kB * 512 + (((((nB >> 3) + 1) ^ swzB) & 31) << 4);

  const int NT = 16;   // 512 / BK32

#define AGU_BLOAD(dst, t)                                                   \
  { const f4* p_ = (const f4*)(Wrow + (size_t)(t) * 32 * HEXP);             \
    dst[0] = p_[0]; dst[1] = p_[1]; dst[2] = p_[2]; dst[3] = p_[3]; }

#define AGU_BWRITE(buf, src)                                                \
  { unsigned u0_, u1_, u2_, u3_;                                            \
    asm("v_cvt_pk_bf16_f32 %0, %1, %2" : "=v"(u0_) : "v"(src[0][0]), "v"(src[0][1])); \
    asm("v_cvt_pk_bf16_f32 %0, %1, %2" : "=v"(u1_) : "v"(src[0][2]), "v"(src[0][3])); \
    asm("v_cvt_pk_bf16_f32 %0, %1, %2" : "=v"(u2_) : "v"(src[1][0]), "v"(src[1][1])); \
    asm("v_cvt_pk_bf16_f32 %0, %1, %2" : "=v"(u3_) : "v"(src[1][2]), "v"(src[1][3])); \
    uint4v v0_ = {u0_, u1_, u2_, u3_};                                      \
    asm("v_cvt_pk_bf16_f32 %0, %1, %2" : "=v"(u0_) : "v"(src[2][0]), "v"(src[2][1])); \
    asm("v_cvt_pk_bf16_f32 %0, %1, %2" : "=v"(u1_) : "v"(src[2][2]), "v"(src[2][3])); \
    asm("v_cvt_pk_bf16_f32 %0, %1, %2" : "=v"(u2_) : "v"(src[3][0]), "v"(src[3][1])); \
    asm("v_cvt_pk_bf16_f32 %0, %1, %2" : "=v"(u3_) : "v"(src[3][2]), "v"(src[3][3])); \
    uint4v v1_ = {u0_, u1_, u2_, u3_};                                      \
    *(short8*)((char*)(buf) + wb_off)  = __builtin_bit_cast(short8, v0_);   \
    *(short8*)((char*)(buf) + wb_off2) = __builtin_bit_cast(short8, v1_); }

  // A staging: wave wv stages rows wv*16 .. wv*16+15; lane: row = wv*16+(lane>>2),
  // 16B chunk = lane&3, source pre-swizzled to match frag_ldA.
  // NOTE: aptr is unsigned short* — k advance is t*32 ELEMENTS (R7 bug: *2).
#define AGU_AISSUE(buf, t) GLDS16(aptr + (size_t)(t) * 32, (unsigned short*)(buf) + wv * 512)

#define AGU_MMA(la, lb)                                                     \
  { short8 afr_[4];                                                         \
    _Pragma("unroll")                                                       \
    for (int mf = 0; mf < 4; ++mf) afr_[mf] = frag_ldA((la), wm + mf * 16 + r16, kb); \
    _Pragma("unroll")                                                       \
    for (int nf = 0; nf < 4; ++nf) {                                        \
      int n_ = wn + nf * 16 + r16;                                          \
      short8 bfr_;                                                          \
      _Pragma("unroll")                                                     \
      for (int j = 0; j < 8; ++j) {                                         \
        int k_ = kb + j;                                                    \
        int ch_ = (((n_ >> 3) ^ (k_ & 7) ^ ((k_ >> 3) << 1)) & 31);         \
        bfr_[j] = *(const short*)((const char*)(lb) + k_ * 512 + (ch_ << 4) + (n_ & 7) * 2); \
      }                                                                     \
      _Pragma("unroll")                                                     \
      for (int mf = 0; mf < 4; ++mf)                                        \
        acc[mf][nf] = __builtin_amdgcn_mfma_f32_16x16x32_bf16(afr_[mf], bfr_, acc[mf][nf], 0, 0, 0); \
    } }

  for (int m0 = 0; m0 < ne; m0 += 128) {
    // per-m0 A source pointer (gathered row, pre-swizzled chunk)
    int arow = wv * 16 + (lane >> 2);
    int srow = lst[min(m0 + arow, ne - 1)];
    const unsigned short* aptr = xbf + (size_t)srow * DM + kr
                               + (((lane & 3) ^ ((arow >> 1) & 3)) << 3);
    f32x4 acc[4][4] = {};
    f4 br0[4], br1[4];
    // prologue: B(0), A(0), B(1), A(1)  (order pinned by MEMCLOB)
    AGU_BLOAD(br0, 0) MEMCLOB();
    AGU_AISSUE(lA[0], 0); MEMCLOB();
    AGU_BLOAD(br1, 1) MEMCLOB();
    AGU_AISSUE(lA[1], 1); MEMCLOB();
    VMWAIT(6);                 // B(0) landed
    AGU_BWRITE(lB[0], br0)
    VMWAIT(5);                 // A(0) landed
    LGKM0(); BARX();
    // in flight: B(1)x4 + A(1)x1
#pragma unroll 1
    for (int t = 0; t < NT; t += 2) {
      // ---- step t (even): bufs[0]
      AGU_MMA(lA[0], lB[0])
      {
        VMWAIT(1);             // B(t+1) in br1
        AGU_BWRITE(lB[1], br1)
        VMWAIT(0);             // A(t+1) landed
        LGKM0(); BARX();
        if (t + 2 < NT) {
          AGU_BLOAD(br0, t + 2) MEMCLOB();
          AGU_AISSUE(lA[0], t + 2); MEMCLOB();
        }
      }
      // ---- step t+1 (odd): bufs[1]
      AGU_MMA(lA[1], lB[1])
      if (t + 1 < NT - 1) {
        VMWAIT(1);             // B(t+2) in br0
        AGU_BWRITE(lB[0], br0)
        VMWAIT(0);             // A(t+2) landed
        LGKM0(); BARX();
        if (t + 3 < NT) {
          AGU_BLOAD(br1, t + 3) MEMCLOB();
          AGU_AISSUE(lA[1], t + 3); MEMCLOB();
        }
      }
    }
    // epilogue: atomic accumulate partials
#pragma unroll
    for (int mf = 0; mf < 4; ++mf)
#pragma unroll
      for (int nf = 0; nf < 4; ++nf)
#pragma unroll
        for (int rr = 0; rr < 4; ++rr) {
          int rl = m0 + wm + mf * 16 + (lane >> 4) * 4 + rr;
          if (rl < ne) {
            int col = nr + wn + nf * 16 + r16;
            atomicAdd(accb + (size_t)(base + rl) * HEXP + col, acc[mf][nf][rr]);
          }
        }
    BARX();   // protect LDS reuse across m0 iterations
  }
#undef AGU_BLOAD
#undef AGU_BWRITE
#undef AGU_AISSUE
#undef AGU_MMA
}

// ---------------------------------------------------------------- swiglu epilogue
__global__ __launch_bounds__(256) void k_swiglu(const float* __restrict__ accg,
    const float* __restrict__ accu, const int* __restrict__ offs,
    unsigned short* __restrict__ hws) {
  int total = offs[NEXP];
  int gid = blockIdx.x * 256 + threadIdx.x;
  int row = gid >> 6;
  if (row >= total) return;
  int c0 = (gid & 63) * 8;
  size_t o = (size_t)row * HEXP + c0;
  f4 g0 = *(const f4*)(accg + o), g1 = *(const f4*)(accg + o + 4);
  f4 u0 = *(const f4*)(accu + o), u1 = *(const f4*)(accu + o + 4);
  short8 out;
  out[0] = f2bf(silu_mul(g0[0], u0[0])); out[1] = f2bf(silu_mul(g0[1], u0[1]));
  out[2] = f2bf(silu_mul(g0[2], u0[2])); out[3] = f2bf(silu_mul(g0[3], u0[3]));
  out[4] = f2bf(silu_mul(g1[0], u1[0])); out[5] = f2bf(silu_mul(g1[1], u1[1]));
  out[6] = f2bf(silu_mul(g1[2], u1[2])); out[7] = f2bf(silu_mul(g1[3], u1[3]));
  *(short8*)(hws + o) = out;
}

// ---------------------------------------------------------------- shared gate+up (R4)
__global__ __launch_bounds__(256, 3) void k_shared_gateup(const unsigned short* __restrict__ xbf,
    const float* __restrict__ Sg, const float* __restrict__ Su,
    unsigned short* __restrict__ hs) {
  int n0 = blockIdx.x * 64;
  int m0 = blockIdx.y * 128;
  int s  = blockIdx.z;
  const float* Bg = Sg + (size_t)s * DM * HSH;
  const float* Bu = Su + (size_t)s * DM * HSH;
  __shared__ unsigned short lA[2][128 * 32];
  __shared__ float lBg[2][32 * 64];
  __shared__ float lBu[2][32 * 64];
  int tid = threadIdx.x;
  int lane = tid & 63, wv = tid >> 6;
  int wm = (wv >> 1) * 64, wn = (wv & 1) * 32;
  const unsigned short* Abase = xbf; const int lda = DM;
  B_SETUP(bgsrc, Bg, HSH)
  B_SETUP(busrc, Bu, HSH)
  A_SETUP(asrc, m0 + row)
  f32x4 accg[4][2] = {};
  f32x4 accu[4][2] = {};
  const int NT = DM / 32;
  A_STAGE(asrc, lA[0], 0)  B_STAGE(bgsrc, lBg[0], 0, HSH)  B_STAGE(busrc, lBu[0], 0, HSH)
  A_STAGE(asrc, lA[1], 32) B_STAGE(bgsrc, lBg[1], 32, HSH) B_STAGE(busrc, lBu[1], 32, HSH)
  VMWAIT(6); BARX();
#pragma unroll 1
  for (int t = 0; t < NT; t += 2) {
    mma2f(lA[0], lBg[0], lBu[0], accg, accu, wm, wn, lane);
    BARX();
    if (t + 2 < NT) {
      int k2 = (t + 2) * 32;
      A_STAGE(asrc, lA[0], k2) B_STAGE(bgsrc, lBg[0], k2, HSH) B_STAGE(busrc, lBu[0], k2, HSH)
      VMWAIT(6);
    } else { VMWAIT(0); }
    BARX();
    mma2f(lA[1], lBg[1], lBu[1], accg, accu, wm, wn, lane);
    if (t + 2 < NT) {
      BARX();
      if (t + 3 < NT) {
        int k3 = (t + 3) * 32;
        A_STAGE(asrc, lA[1], k3) B_STAGE(bgsrc, lBg[1], k3, HSH) B_STAGE(busrc, lBu[1], k3, HSH)
        VMWAIT(6);
      } else { VMWAIT(0); }
      BARX();
    }
  }
#pragma unroll
  for (int mf = 0; mf < 4; ++mf)
#pragma unroll
    for (int nf = 0; nf < 2; ++nf)
#pragma unroll
      for (int r = 0; r < 4; ++r) {
        int row = m0 + wm + mf * 16 + (lane >> 4) * 4 + r;
        int col = n0 + wn + nf * 16 + (lane & 15);
        float h = silu_mul(accg[mf][nf][r], accu[mf][nf][r]);
        hs[(size_t)row * (NSH * HSH) + s * HSH + col] = f2bf(h);
      }
}

// ---------------------------------------------------------------- shared down (R4)
__global__ __launch_bounds__(256, 4) void k_shared_down(const unsigned short* __restrict__ hs,
    const float* __restrict__ Sd, float* __restrict__ out) {
  int n0 = blockIdx.x * 64;
  int m0 = blockIdx.y * 128;
  __shared__ unsigned short lA[2][128 * 32];
  __shared__ float lB[2][32 * 64];
  int tid = threadIdx.x;
  int lane = tid & 63, wv = tid >> 6;
  int wm = (wv >> 1) * 64, wn = (wv & 1) * 32;
  const unsigned short* Abase = hs; const int lda = NSH * HSH;
  B_SETUP(bsrc, Sd, DM)
  A_SETUP(asrc, m0 + row)
  f32x4 acc[4][2] = {};
  const int NT = (NSH * HSH) / 32;
  A_STAGE(asrc, lA[0], 0)  B_STAGE(bsrc, lB[0], 0, DM)
  A_STAGE(asrc, lA[1], 32) B_STAGE(bsrc, lB[1], 32, DM)
  VMWAIT(4); BARX();
#pragma unroll 1
  for (int t = 0; t < NT; t += 2) {
    mma1f(lA[0], lB[0], acc, wm, wn, lane);
    BARX();
    if (t + 2 < NT) {
      int k2 = (t + 2) * 32;
      A_STAGE(asrc, lA[0], k2) B_STAGE(bsrc, lB[0], k2, DM)
      VMWAIT(4);
    } else { VMWAIT(0); }
    BARX();
    mma1f(lA[1], lB[1], acc, wm, wn, lane);
    if (t + 2 < NT) {
      BARX();
      if (t + 3 < NT) {
        int k3 = (t + 3) * 32;
        A_STAGE(asrc, lA[1], k3) B_STAGE(bsrc, lB[1], k3, DM)
        VMWAIT(4);
      } else { VMWAIT(0); }
      BARX();
    }
  }
#pragma unroll
  for (int mf = 0; mf < 4; ++mf)
#pragma unroll
    for (int nf = 0; nf < 2; ++nf)
#pragma unroll
      for (int r = 0; r < 4; ++r) {
        int row = m0 + wm + mf * 16 + (lane >> 4) * 4 + r;
        int col = n0 + wn + nf * 16 + (lane & 15);
        out[(size_t)row * DM + col] = acc[mf][nf][r];
      }
}

// ---------------------------------------------------------------- expert down (R4)
__global__ __launch_bounds__(256, 4) void k_expert_down(const unsigned short* __restrict__ hws,
    const float* __restrict__ Wd, const int* __restrict__ cnt, const int* __restrict__ offs,
    const int* __restrict__ lists, const float* __restrict__ wlist,
    float* __restrict__ out) {
  int e = blockIdx.y;
  int ne = min(cnt[e], CAPC);
  if (ne == 0) return;
  int n0 = blockIdx.x * 64;
  const float* B = Wd + (size_t)e * HEXP * DM;
  __shared__ unsigned short lA[2][128 * 32];
  __shared__ float lB[2][32 * 64];
  int tid = threadIdx.x;
  int lane = tid & 63, wv = tid >> 6;
  int wm = (wv >> 1) * 64, wn = (wv & 1) * 32;
  const unsigned short* Abase = hws + (size_t)offs[e] * HEXP; const int lda = HEXP;
  B_SETUP(bsrc, B, DM)
  const int NT = HEXP / 32;
  for (int m0 = 0; m0 < ne; m0 += 128) {
    A_SETUP(asrc, min(m0 + row, ne - 1))
    f32x4 acc[4][2] = {};
    A_STAGE(asrc, lA[0], 0)  B_STAGE(bsrc, lB[0], 0, DM)
    A_STAGE(asrc, lA[1], 32) B_STAGE(bsrc, lB[1], 32, DM)
    VMWAIT(4); BARX();
#pragma unroll 1
    for (int t = 0; t < NT; t += 2) {
      mma1f(lA[0], lB[0], acc, wm, wn, lane);
      BARX();
      if (t + 2 < NT) {
        int k2 = (t + 2) * 32;
        A_STAGE(asrc, lA[0], k2) B_STAGE(bsrc, lB[0], k2, DM)
        VMWAIT(4);
      } else { VMWAIT(0); }
      BARX();
      mma1f(lA[1], lB[1], acc, wm, wn, lane);
      if (t + 2 < NT) {
        BARX();
        if (t + 3 < NT) {
          int k3 = (t + 3) * 32;
          A_STAGE(asrc, lA[1], k3) B_STAGE(bsrc, lB[1], k3, DM)
          VMWAIT(4);
        } else { VMWAIT(0); }
        BARX();
      }
    }
    BARX();
#pragma unroll
    for (int mf = 0; mf < 4; ++mf)
#pragma unroll
      for (int r = 0; r < 4; ++r) {
        int rl = m0 + wm + mf * 16 + (lane >> 4) * 4 + r;
        if (rl < ne) {
          int tok  = lists[e * CAPC + rl];
          float w  = wlist[e * CAPC + rl];
#pragma unroll
          for (int nf = 0; nf < 2; ++nf) {
            int col = n0 + wn + nf * 16 + (lane & 15);
            atomicAdd(out + (size_t)tok * DM + col, acc[mf][nf][r] * w);
          }
        }
      }
  }
}

// ---------------------------------------------------------------- launch
extern "C" void kernel_launch(void* const* d_in, const int* in_sizes, int n_in,
                              void* d_out, int out_size, void* d_ws, size_t ws_size,
                              hipStream_t stream) {
  const float* x    = (const float*)d_in[0];
  const float* Wr   = (const float*)d_in[1];
  const float* bias = (const float*)d_in[2];
  const float* Wg   = (const float*)d_in[3];
  const float* Wu   = (const float*)d_in[4];
  const float* Wd   = (const float*)d_in[5];
  const float* Sg   = (const float*)d_in[6];
  const float* Su   = (const float*)d_in[7];
  const float* Sd   = (const float*)d_in[8];
  float* out = (float*)d_out;
  char* ws = (char*)d_ws;

  const size_t off_cnt   = 0;
  const size_t off_offs  = 256;
  const size_t off_lists = 1024;
  const size_t off_wlist = off_lists + (size_t)NEXP * CAPC * 4;
  const size_t off_xbf   = off_wlist + (size_t)NEXP * CAPC * 4;
  const size_t off_hs    = off_xbf + (size_t)N_TOK * DM * 2;
  const size_t off_h     = off_hs + (size_t)N_TOK * NSH * HSH * 2;
  const size_t off_accg  = (off_h + (size_t)N_TOK * TOPK * HEXP * 2 + 255) & ~(size_t)255;
  const size_t off_accu  = off_accg + (size_t)N_TOK * TOPK * HEXP * 4;
  const size_t req       = off_accu + (size_t)N_TOK * TOPK * HEXP * 4;
  if (ws_size < req) return;

  int* cnt            = (int*)(ws + off_cnt);
  int* offs           = (int*)(ws + off_offs);
  int* lists          = (int*)(ws + off_lists);
  float* wlist        = (float*)(ws + off_wlist);
  unsigned short* xbf = (unsigned short*)(ws + off_xbf);
  unsigned short* hs  = (unsigned short*)(ws + off_hs);
  unsigned short* hws = (unsigned short*)(ws + off_h);
  float* accg         = (float*)(ws + off_accg);
  float* accu         = (float*)(ws + off_accu);

  hipMemsetAsync(cnt, 0, NEXP * sizeof(int), stream);
  hipMemsetAsync(accg, 0, (size_t)N_TOK * TOPK * HEXP * 8, stream);  // accg+accu contiguous
  k_convert<<<(N_TOK * DM) / (256 * 8), 256, 0, stream>>>(x, xbf);
  k_router<<<N_TOK / RTB, 256, 0, stream>>>(x, Wr, bias, cnt, lists, wlist);
  k_offs<<<1, 64, 0, stream>>>(cnt, offs);
  k_expert_gu_mm<<<NEXP * 2 * 4 * 2, 512, 0, stream>>>(xbf, Wg, Wu, cnt, offs, lists, accg, accu);
  k_swiglu<<<(N_TOK * TOPK * HEXP / 8) / 256, 256, 0, stream>>>(accg, accu, offs, hws);
  k_shared_gateup<<<dim3(HSH / 64, N_TOK / 128, NSH), 256, 0, stream>>>(xbf, Sg, Su, hs);
  k_shared_down<<<dim3(DM / 64, N_TOK / 128), 256, 0, stream>>>(hs, Sd, out);
  k_expert_down<<<dim3(DM / 64, NEXP), 256, 0, stream>>>(hws, Wd, cnt, offs, lists, wlist, out);
}